// Round 9
// baseline (8064.566 us; speedup 1.0000x reference)
//
#include <hip/hip_runtime.h>

// 2-layer LSTM (B=200,T=250,F=14,H=256) + Dense(164,relu) + Dense(8,softmax)
//
// v8: block-local recurrences (the structural fix).
//  - 13 L1 blocks + 13 L2 blocks, 1024 threads (16 waves) each; group g's
//    16 batch rows handled by one block per layer.
//  - L1: h1 recurrence entirely in LDS (double-buffered, XOR-swizzled
//    [16][256] bf16). No polls, no global reads on the chain; one barrier
//    per step. Streams h1_t to seq[t] (sc01 write-through) and posts the
//    step-t flag at step t+1 (store-drain off the critical path).
//  - L2: h2 recurrence in LDS; h1_t arrives via registers prefetched one
//    step ahead (L1 runs ahead -> poll is a hit; fetch hidden under MFMA).
//    Only the FINAL h2 goes to global (head input).
//  - No placement assumptions; L1 waits on nothing, L2 only on L1 -> no
//    deadlock under any block->XCD/CU mapping. Flags zeroed by prep,
//    slabs write-once, flags monotonic.

#define T_STEPS 250
#define B_REAL  200
#define BPAD    208
#define FIN     14
#define HID     256
#define NGATE   1024
#define NBG     13
#define SLAB    (BPAD*HID)
#define XT_ROW  32
#define XT_ELEMS (T_STEPS*BPAD*XT_ROW)
#define FSTRIDE 32
#define NF      16
#define F1N     ((long long)T_STEPS*NBG*FSTRIDE)

typedef __bf16 bf16_t;
typedef __bf16 bf16x8 __attribute__((ext_vector_type(8)));
typedef float  f32x4  __attribute__((ext_vector_type(4)));

__device__ __forceinline__ float sigmoid_f(float x) {
  return 1.f / (1.f + __expf(-x));
}
__device__ __forceinline__ float tanh_f(float x) {
  float e = __expf(2.f * x);
  return 1.f - 2.f / (e + 1.f);
}

__device__ __forceinline__ unsigned int ld_flag_sc01(const unsigned int* p) {
  unsigned int v;
  asm volatile("global_load_dword %0, %1, off sc0 sc1\n\ts_waitcnt vmcnt(0)"
               : "=v"(v) : "v"(p) : "memory");
  return v;
}
__device__ __forceinline__ void st_flag_sc01(unsigned int* p) {
  unsigned int one = 1u;
  asm volatile("global_store_dword %0, %1, off sc0 sc1" :: "v"(p), "v"(one) : "memory");
}
__device__ __forceinline__ void st_bf16_sc01(bf16_t* p, bf16_t v) {
  unsigned int u = (unsigned int)__builtin_bit_cast(unsigned short, v);
  asm volatile("global_store_short %0, %1, off sc0 sc1" :: "v"(p), "v"(u) : "memory");
}
__device__ __forceinline__ void waitcnt0() {
  asm volatile("s_waitcnt vmcnt(0)" ::: "memory");
}

// all 16 per-wave flags of `rec` set? lanes 0..15 poll (MALL-coherent).
__device__ __forceinline__ void poll16(const unsigned int* rec, int l) {
  for (;;) {
    unsigned int v = 1u;
    if (l < NF) v = ld_flag_sc01(rec + l);
    if (__all(v != 0u)) return;
  }
}

__device__ __forceinline__ long long fidx(int t, int g) {
  return ((long long)t * NBG + g) * FSTRIDE;
}
// swizzled LDS element index for [16][256] bf16 (breaks 512B-row bank aliasing)
__device__ __forceinline__ int SW(int row, int col) {
  return row * 256 + (col ^ ((row & 7) << 3));
}

// ---------------------------------------------------------------- prep
__global__ void prep_kernel(const float* __restrict__ x,
                            bf16_t* __restrict__ xT,
                            unsigned int* __restrict__ f1)
{
  long long i = (long long)blockIdx.x * blockDim.x + threadIdx.x;
  const long long total = (long long)XT_ELEMS + F1N;
  if (i >= total) return;
  if (i < XT_ELEMS) {
    int t  = (int)(i / (BPAD * XT_ROW));
    int r  = (int)(i % (BPAD * XT_ROW));
    int b  = r / XT_ROW, kk = r % XT_ROW;
    float v = 0.f;
    if (b < B_REAL && kk < FIN) v = x[((long long)b * T_STEPS + t) * FIN + kk];
    xT[i] = (bf16_t)v;
    return;
  }
  f1[i - XT_ELEMS] = 0u;
}

// ---------------------------------------------------------------- fused LSTM
__global__ __launch_bounds__(1024) void lstm_fused(
    const float* __restrict__ W1, const float* __restrict__ U1,
    const float* __restrict__ b1,
    const float* __restrict__ W2, const float* __restrict__ U2,
    const float* __restrict__ b2,
    const bf16_t* __restrict__ xT,
    bf16_t* __restrict__ seq,        // [250][208][256] h1_t
    bf16_t* __restrict__ h2f,        // [208][256] final h2
    unsigned int* __restrict__ f1)
{
  __shared__ bf16_t hsA[16 * 256];
  __shared__ bf16_t hsB[16 * 256];
  const int tid = threadIdx.x;
  const int l   = tid & 63;
  const int lr  = l & 15;
  const int ag  = l >> 4;
  const int w   = tid >> 6;            // 0..15
  const int unit = w * 16 + lr;        // 0..255

  if (blockIdx.x < NBG) {
    // ================= layer 1 (self-contained, free-running) =============
    const int g  = blockIdx.x;
    const int b0 = g * 16;

    f32x4 wb[4][9];
#pragma unroll
    for (int gg = 0; gg < 4; ++gg) {
      const int n = gg * 256 + unit;
#pragma unroll
      for (int kf = 0; kf < 9; ++kf) {
        bf16x8 v;
#pragma unroll
        for (int e = 0; e < 8; ++e) {
          const int k = kf * 32 + ag * 8 + e;
          float val = 0.f;
          if (k < 256)            val = U1[(long long)k * NGATE + n];
          else if (k - 256 < FIN) val = W1[(long long)(k - 256) * NGATE + n];
          v[e] = (bf16_t)val;
        }
        wb[gg][kf] = __builtin_bit_cast(f32x4, v);
      }
    }
    float bias[4];
#pragma unroll
    for (int gg = 0; gg < 4; ++gg) bias[gg] = b1[gg * 256 + unit];
    float cst[4] = {0.f, 0.f, 0.f, 0.f};

    for (int i = tid; i < 16 * 256; i += 1024) hsA[i] = (bf16_t)0.f;  // h1_0
    __syncthreads();

    auto step = [&](int t, const bf16_t* RD, bf16_t* WR) {
      // x_t load issued first; consumed by the last MFMA (latency hidden)
      const bf16x8 ax = *(const bf16x8*)(xT + ((long long)t * BPAD + b0 + lr) * XT_ROW + ag * 8);
      f32x4 acc[4];
#pragma unroll
      for (int gg = 0; gg < 4; ++gg)
        acc[gg] = (f32x4){bias[gg], bias[gg], bias[gg], bias[gg]};
#pragma unroll
      for (int kf = 0; kf < 8; ++kf) {
        const bf16x8 a = *(const bf16x8*)(RD + lr * 256 + ((kf * 32 + ag * 8) ^ ((lr & 7) << 3)));
#pragma unroll
        for (int gg = 0; gg < 4; ++gg)
          acc[gg] = __builtin_amdgcn_mfma_f32_16x16x32_bf16(
              a, __builtin_bit_cast(bf16x8, wb[gg][kf]), acc[gg], 0, 0, 0);
      }
#pragma unroll
      for (int gg = 0; gg < 4; ++gg)
        acc[gg] = __builtin_amdgcn_mfma_f32_16x16x32_bf16(
            ax, __builtin_bit_cast(bf16x8, wb[gg][8]), acc[gg], 0, 0, 0);

      bf16_t hv[4];
#pragma unroll
      for (int r = 0; r < 4; ++r) {
        const float ig = sigmoid_f(acc[0][r]);
        const float fg = sigmoid_f(acc[1][r]);
        const float gg = tanh_f  (acc[2][r]);
        const float og = sigmoid_f(acc[3][r]);
        const float c  = fg * cst[r] + ig * gg;
        cst[r] = c;
        hv[r] = (bf16_t)(og * tanh_f(c));
      }
      // delayed flag: step t-1's stores have had a full step to drain
      waitcnt0();
      if (l == 0 && t > 0) st_flag_sc01(f1 + fidx(t - 1, g) + w);
      bf16_t* orow = seq + (long long)t * SLAB;
#pragma unroll
      for (int r = 0; r < 4; ++r)
        st_bf16_sc01(orow + (b0 + ag * 4 + r) * HID + unit, hv[r]);
#pragma unroll
      for (int r = 0; r < 4; ++r)
        WR[SW(ag * 4 + r, unit)] = hv[r];
      __syncthreads();
    };

    for (int t = 0; t < T_STEPS; t += 2) {
      step(t,     hsA, hsB);
      step(t + 1, hsB, hsA);
    }
    waitcnt0();
    if (l == 0) st_flag_sc01(f1 + fidx(T_STEPS - 1, g) + w);
  } else {
    // ================= layer 2 (LDS recurrence + h1 prefetch) =============
    const int g  = blockIdx.x - NBG;
    const int b0 = g * 16;

    // wb[gate][kf]: kf 0..7 = U2 (h2 part), kf 8..15 = W2 (h1 part)
    f32x4 wb[4][16];
#pragma unroll
    for (int gg = 0; gg < 4; ++gg) {
      const int n = gg * 256 + unit;
#pragma unroll
      for (int kf = 0; kf < 16; ++kf) {
        const float* Wsrc = (kf < 8) ? U2 : W2;
        const int kb = (kf & 7) * 32 + ag * 8;
        bf16x8 v;
#pragma unroll
        for (int e = 0; e < 8; ++e)
          v[e] = (bf16_t)Wsrc[(long long)(kb + e) * NGATE + n];
        wb[gg][kf] = __builtin_bit_cast(f32x4, v);
      }
    }
    float bias[4];
#pragma unroll
    for (int gg = 0; gg < 4; ++gg) bias[gg] = b2[gg * 256 + unit];
    float cst[4] = {0.f, 0.f, 0.f, 0.f};

    for (int i = tid; i < 16 * 256; i += 1024) hsA[i] = (bf16_t)0.f;  // h2_0
    __syncthreads();

    // prologue: h1_0 into cur regs
    poll16(f1 + fidx(0, g), l);
    bf16x8 ha[8], hb[8];
#pragma unroll
    for (int j = 0; j < 8; ++j)
      ha[j] = *(const bf16x8*)(seq + (b0 + lr) * HID + j * 32 + ag * 8);

    auto step = [&](int t, const bf16_t* RD, bf16_t* WR,
                    bf16x8 (&cur)[8], bf16x8 (&nxt)[8]) {
      if (t + 1 < T_STEPS) {
        poll16(f1 + fidx(t + 1, g), l);          // L1 runs ahead: usually a hit
        const bf16_t* nrow = seq + (long long)(t + 1) * SLAB + (b0 + lr) * HID;
#pragma unroll
        for (int j = 0; j < 8; ++j)              // prefetch h1_{t+1}
          nxt[j] = *(const bf16x8*)(nrow + j * 32 + ag * 8);
      }
      f32x4 acc[4];
#pragma unroll
      for (int gg = 0; gg < 4; ++gg)
        acc[gg] = (f32x4){bias[gg], bias[gg], bias[gg], bias[gg]};
#pragma unroll
      for (int kf = 0; kf < 8; ++kf) {           // h2_t @ U2 (LDS)
        const bf16x8 a = *(const bf16x8*)(RD + lr * 256 + ((kf * 32 + ag * 8) ^ ((lr & 7) << 3)));
#pragma unroll
        for (int gg = 0; gg < 4; ++gg)
          acc[gg] = __builtin_amdgcn_mfma_f32_16x16x32_bf16(
              a, __builtin_bit_cast(bf16x8, wb[gg][kf]), acc[gg], 0, 0, 0);
      }
#pragma unroll
      for (int kf = 0; kf < 8; ++kf) {           // h1_t @ W2 (regs)
#pragma unroll
        for (int gg = 0; gg < 4; ++gg)
          acc[gg] = __builtin_amdgcn_mfma_f32_16x16x32_bf16(
              cur[kf], __builtin_bit_cast(bf16x8, wb[gg][kf + 8]), acc[gg], 0, 0, 0);
      }
      bf16_t hv[4];
#pragma unroll
      for (int r = 0; r < 4; ++r) {
        const float ig = sigmoid_f(acc[0][r]);
        const float fg = sigmoid_f(acc[1][r]);
        const float gg = tanh_f  (acc[2][r]);
        const float og = sigmoid_f(acc[3][r]);
        const float c  = fg * cst[r] + ig * gg;
        cst[r] = c;
        hv[r] = (bf16_t)(og * tanh_f(c));
      }
      if (t == T_STEPS - 1) {
#pragma unroll
        for (int r = 0; r < 4; ++r)              // final h2 only (plain)
          h2f[(b0 + ag * 4 + r) * HID + unit] = hv[r];
      }
#pragma unroll
      for (int r = 0; r < 4; ++r)
        WR[SW(ag * 4 + r, unit)] = hv[r];
      __syncthreads();
    };

    for (int t = 0; t < T_STEPS; t += 2) {
      step(t,     hsA, hsB, ha, hb);
      step(t + 1, hsB, hsA, hb, ha);
    }
  }
}

// ---------------------------------------------------------------- head
__global__ __launch_bounds__(64) void head_kernel(
    const bf16_t* __restrict__ h2,
    const float* __restrict__ Wd, const float* __restrict__ bd,
    const float* __restrict__ Ws, const float* __restrict__ bs,
    float* __restrict__ out)
{
  __shared__ float hsm[HID];
  __shared__ float hid[164];
  __shared__ float lg[8];
  const int b = blockIdx.x, tid = threadIdx.x;
  const bf16_t* hr = h2 + (long long)b * HID;
  for (int k = tid; k < HID; k += 64) hsm[k] = (float)hr[k];
  __syncthreads();
  for (int d = tid; d < 164; d += 64) {
    float a = bd[d];
    for (int k = 0; k < HID; ++k) a = fmaf(hsm[k], Wd[k * 164 + d], a);
    hid[d] = fmaxf(a, 0.f);
  }
  __syncthreads();
  if (tid < 8) {
    float a = bs[tid];
    for (int k = 0; k < 164; ++k) a = fmaf(hid[k], Ws[k * 8 + tid], a);
    lg[tid] = a;
  }
  __syncthreads();
  if (tid < 8) {
    float m = lg[0];
#pragma unroll
    for (int j = 1; j < 8; ++j) m = fmaxf(m, lg[j]);
    float s = 0.f;
#pragma unroll
    for (int j = 0; j < 8; ++j) s += __expf(lg[j] - m);
    out[b * 8 + tid] = __expf(lg[tid] - m) / s;
  }
}

// ---------------------------------------------------------------- launch
extern "C" void kernel_launch(void* const* d_in, const int* in_sizes, int n_in,
                              void* d_out, int out_size, void* d_ws, size_t ws_size,
                              hipStream_t stream)
{
  const float* x  = (const float*)d_in[0];
  const float* W1 = (const float*)d_in[1];
  const float* U1 = (const float*)d_in[2];
  const float* b1 = (const float*)d_in[3];
  const float* W2 = (const float*)d_in[4];
  const float* U2 = (const float*)d_in[5];
  const float* b2 = (const float*)d_in[6];
  const float* Wd = (const float*)d_in[7];
  const float* bd = (const float*)d_in[8];
  const float* Ws = (const float*)d_in[9];
  const float* bs = (const float*)d_in[10];
  (void)in_sizes; (void)n_in; (void)out_size; (void)ws_size;

  char* p = (char*)d_ws;
  size_t off = 0;
  auto carve = [&](size_t bytes) -> void* {
    void* r = p + off;
    off = (off + bytes + 255) & ~(size_t)255;
    return r;
  };
  bf16_t* xT  = (bf16_t*)carve((size_t)XT_ELEMS * 2);
  bf16_t* seq = (bf16_t*)carve((size_t)T_STEPS * SLAB * 2);
  bf16_t* h2f = (bf16_t*)carve((size_t)SLAB * 2);
  unsigned int* f1 = (unsigned int*)carve((size_t)F1N * 4);

  const long long prep_total = (long long)XT_ELEMS + F1N;
  const int pb = (int)((prep_total + 255) / 256);

  prep_kernel<<<pb, 256, 0, stream>>>(x, xT, f1);
  lstm_fused<<<2 * NBG, 1024, 0, stream>>>(W1, U1, b1, W2, U2, b2,
                                           xT, seq, h2f, f1);
  head_kernel<<<B_REAL, 64, 0, stream>>>(h2f, Wd, bd, Ws, bs, (float*)d_out);
}